// Round 11
// baseline (295.545 us; speedup 1.0000x reference)
//
#include <hip/hip_runtime.h>
#include <hip/hip_bf16.h>
#include <stdint.h>

typedef unsigned short u16;
typedef __attribute__((ext_vector_type(8))) short bf16x8;
typedef __attribute__((ext_vector_type(4))) float f32x4;

#define S_LEN 577
#define DMODEL 768
#define NHEAD 12
#define DH 64
#define BATCH 16
#define M_ROWS (BATCH * S_LEN)   /* 9232 */
#define M_PAD 9344               /* 73 * 128 */
#define VT_STRIDE 640            /* padded S so 16B frag loads stay aligned */
#define CEXPF 0.18033688f        /* 0.125 * log2(e), folded into Q at the GEMM */

__device__ __forceinline__ u16 f2bu(float f) {
  uint32_t u = __float_as_uint(f);
  u += 0x7FFFu + ((u >> 16) & 1u);      // RNE; inputs are finite
  return (u16)(u >> 16);
}
__device__ __forceinline__ float bu2f(u16 b) {
  return __uint_as_float(((uint32_t)b) << 16);
}
// async global->LDS, 16B per lane; LDS dest = wave-uniform base + lane*16
__device__ __forceinline__ void gl2lds16(const u16* g, u16* l) {
  __builtin_amdgcn_global_load_lds(
      (const __attribute__((address_space(1))) unsigned int*)g,
      (__attribute__((address_space(3))) unsigned int*)l, 16, 0, 0);
}

// ---------------- prep: x fp32 -> bf16 [M_PAD,768], pad rows zeroed ----------
// R12: also zeroes the gnorm stats buffer (192*2 floats) before attn runs.
__global__ __launch_bounds__(256) void prep_x(const float* __restrict__ x,
                                              u16* __restrict__ xb,
                                              float* __restrict__ stats) {
  if (blockIdx.x == 0 && threadIdx.x < 384) stats[threadIdx.x] = 0.f;
  int e = (blockIdx.x * 256 + threadIdx.x) * 8;
  u16 o[8];
  if (e < M_ROWS * DMODEL) {
    float4 f0 = *(const float4*)(x + e);
    float4 f1 = *(const float4*)(x + e + 4);
    o[0] = f2bu(f0.x); o[1] = f2bu(f0.y); o[2] = f2bu(f0.z); o[3] = f2bu(f0.w);
    o[4] = f2bu(f1.x); o[5] = f2bu(f1.y); o[6] = f2bu(f1.z); o[7] = f2bu(f1.w);
  } else {
#pragma unroll
    for (int i = 0; i < 8; ++i) o[i] = 0;
  }
  *(uint4*)(xb + e) = *(const uint4*)o;
}

// ------------- prep: weights fp32 [K,N] -> bf16 transposed [N,K], tiled ------
// wtqkv rows: [0,1536)=Wq^T, [1536,3072)=Wk^T, [3072,3840)=Wv^T ; wot = Wo^T
__global__ __launch_bounds__(256) void prep_w(
    const float* __restrict__ Wq, const float* __restrict__ Wk,
    const float* __restrict__ Wv, const float* __restrict__ Wo,
    u16* __restrict__ wtqkv, u16* __restrict__ wot) {
  __shared__ u16 tile[32][33];
  int blk = blockIdx.x;
  const float* W; int N; u16* dst; int rowbase;
  if (blk < 1152)      { W = Wq; N = 1536; dst = wtqkv; rowbase = 0; }
  else if (blk < 2304) { W = Wk; N = 1536; dst = wtqkv; rowbase = 1536; blk -= 1152; }
  else if (blk < 2880) { W = Wv; N = 768;  dst = wtqkv; rowbase = 3072; blk -= 2304; }
  else                 { W = Wo; N = 768;  dst = wot;   rowbase = 0;    blk -= 2880; }
  const int ntiles = N >> 5;
  const int tk = blk / ntiles, tn = blk - tk * ntiles;
  const int c = threadIdx.x & 31, r0 = threadIdx.x >> 5;
#pragma unroll
  for (int i = 0; i < 4; ++i) {
    int r = i * 8 + r0;
    tile[r][c] = f2bu(W[(size_t)(tk * 32 + r) * N + tn * 32 + c]);
  }
  __syncthreads();
#pragma unroll
  for (int i = 0; i < 4; ++i) {
    int r = i * 8 + r0;
    dst[(size_t)(rowbase + tn * 32 + r) * 768 + tk * 32 + c] = tile[c][r];
  }
}

// ---------------- bf16 MFMA GEMM: C[M,N] = A[M,768] * Bt[N,768]^T ------------
// mode 0: out fp32 [M_ROWS,N] + biasO[n]  (output projection)
// mode 1: LDS-staged coalesced scatter (R9) -> q1/q2/k1/k2 + vt.
// R10: bijective XCD/chunk swizzle. R12: q1/q2 pre-scaled by CEXPF.
// R14: T2 XOR-swizzle on staging (conflicts 8.18M -> 1.45M).
// R15: T4 counted-vmcnt 3-buffer pipeline. The 2-phase dbuf still exposed
// ~300+ cycles/iter: the barrier's implicit vmcnt(0) drained loads that had
// only the short ds_read+MFMA phase of cover. Now tile k+2 is staged each
// iter (8 loads in flight) and the barrier waits only vmcnt(4) — tile k+1's
// loads, which have had ~2 iterations of cover; k+2's stay in flight ACROSS
// the barrier. Per-wave vmcnt + s_barrier => all waves' k+1 loads complete
// before any wave reads buf[k+1]. sched_barrier(0) fences hoisting (rule 18).
__global__ __launch_bounds__(256, 2) void gemm_bf16(
    const u16* __restrict__ A, const u16* __restrict__ Bt, int N, int mode,
    float* __restrict__ outF, const float* __restrict__ biasO,
    u16* __restrict__ q1p, u16* __restrict__ q2p,
    u16* __restrict__ k1p, u16* __restrict__ k2p, u16* __restrict__ vtp,
    const float* __restrict__ bq, const float* __restrict__ bk,
    const float* __restrict__ bvp) {
  __shared__ __align__(16) u16 smem[24576];  // 48KB: 3 x (lA 4096 | lB 4096)
  const int t = threadIdx.x;
  const int lane = t & 63, wave = t >> 6;
  const int quad = lane >> 4, l16 = lane & 15;
  const int wm = wave & 1, wn = wave >> 1;

  // ---- XCD-locality swizzle (bijective; perf-only) ----
  const int NTg = gridDim.y;
  const int nwg = 73 * NTg;
  const int lin = blockIdx.y * 73 + blockIdx.x;   // dispatch-linear (x fastest)
  const int xcd8 = lin & 7;
  const int idx8 = lin >> 3;
  const int qq = nwg >> 3, rr = nwg & 7;
  const int slot = (xcd8 < rr) ? xcd8 * (qq + 1) + idx8
                               : rr * (qq + 1) + (xcd8 - rr) * qq + idx8;
  const int C = (NTg >= 10) ? 5 : NTg;   // 30 -> 6 chunks of 5; 6 -> 1 chunk
  const int bpc = 73 * C;
  const int chunk = slot / bpc;
  const int rem = slot - chunk * bpc;
  const int mt = rem / C;
  const int nt = chunk * C + (rem - mt * C);
  const int m0 = mt * 128;
  const int n0 = nt * 128;

  f32x4 zero = {0.f, 0.f, 0.f, 0.f};
  f32x4 acc[4][4];
  for (int i = 0; i < 4; ++i) for (int j = 0; j < 4; ++j) acc[i][j] = zero;

  // staging: wave w owns rows w*32..w*32+31 (2 chunks of 16 rows);
  // lane -> row srow, 16B slot (lane&3) XOR'd with (srow>>1)&3 on the SOURCE
  const int srow = wave * 32 + (lane >> 2);
  const int scol = ((lane & 3) ^ ((srow >> 1) & 3)) * 8;
  const u16* gA = A + (size_t)(m0 + srow) * 768 + scol;
  const u16* gB = Bt + (size_t)(n0 + srow) * 768 + scol;
  const int wofs = wave * 1024;
  // read-side swizzled slot offset (constant per lane)
  const int xs = (quad ^ ((l16 >> 1) & 3)) * 8;

  // ---- prologue: stage K-tiles 0 and 1 into bufs 0,1 (8 loads in flight) ----
  {
    u16* sA0 = smem + wofs;
    u16* sB0 = smem + 4096 + wofs;
    gl2lds16(gA, sA0);
    gl2lds16(gA + 16 * 768, sA0 + 512);
    gl2lds16(gB, sB0);
    gl2lds16(gB + 16 * 768, sB0 + 512);
    u16* sA1 = smem + 8192 + wofs;
    u16* sB1 = smem + 8192 + 4096 + wofs;
    gl2lds16(gA + 32, sA1);
    gl2lds16(gA + 32 + 16 * 768, sA1 + 512);
    gl2lds16(gB + 32, sB1);
    gl2lds16(gB + 32 + 16 * 768, sB1 + 512);
  }
  asm volatile("s_waitcnt vmcnt(4)" ::: "memory");   // tile 0 landed
  __builtin_amdgcn_s_barrier();
  __builtin_amdgcn_sched_barrier(0);

  int cur = 0;
  for (int k0 = 0; k0 < 768; k0 += 32) {
    // stage tile k+2 into buf (cur+2)%3 — stays in flight across the barrier
    if (k0 < 704) {
      int nx2 = cur + 2; if (nx2 >= 3) nx2 -= 3;
      u16* sA = smem + nx2 * 8192 + wofs;
      u16* sB = smem + nx2 * 8192 + 4096 + wofs;
      gl2lds16(gA + k0 + 64, sA);
      gl2lds16(gA + k0 + 64 + 16 * 768, sA + 512);
      gl2lds16(gB + k0 + 64, sB);
      gl2lds16(gB + k0 + 64 + 16 * 768, sB + 512);
    }
    const u16* cA = smem + cur * 8192;
    const u16* cB = smem + cur * 8192 + 4096;
    bf16x8 af[4], bfr[4];
#pragma unroll
    for (int i = 0; i < 4; ++i)
      af[i] = *(const bf16x8*)(cA + (wm * 64 + i * 16 + l16) * 32 + xs);
#pragma unroll
    for (int j = 0; j < 4; ++j)
      bfr[j] = *(const bf16x8*)(cB + (wn * 64 + j * 16 + l16) * 32 + xs);
#pragma unroll
    for (int i = 0; i < 4; ++i)
#pragma unroll
      for (int j = 0; j < 4; ++j)
        acc[i][j] = __builtin_amdgcn_mfma_f32_16x16x32_bf16(af[i], bfr[j], acc[i][j], 0, 0, 0);
    // wait only for tile k+1's loads (oldest 4); k+2's 4 stay in flight
    if (k0 < 704) {
      asm volatile("s_waitcnt vmcnt(4)" ::: "memory");
    } else {
      asm volatile("s_waitcnt vmcnt(0)" ::: "memory");
    }
    __builtin_amdgcn_s_barrier();
    __builtin_amdgcn_sched_barrier(0);
    cur = (cur == 2) ? 0 : cur + 1;
  }

  if (mode == 0) {
#pragma unroll
    for (int i = 0; i < 4; ++i) {
#pragma unroll
      for (int j = 0; j < 4; ++j) {
        int n = n0 + wn * 64 + j * 16 + l16;
#pragma unroll
        for (int r = 0; r < 4; ++r) {
          int m = m0 + wm * 64 + i * 16 + quad * 4 + r;
          if (m >= M_ROWS) continue;
          outF[(size_t)m * N + n] = acc[i][j][r] + biasO[n];
        }
      }
    }
    return;
  }

  // ---------------- mode 1 epilogue: LDS-staged coalesced writes ------------
  u16* tile = smem;   // first 16 KB, staging data is dead now
  const bool isv = (n0 >= 3072);
  u16* dstqk = nullptr; const float* biasp = nullptr; int ch0 = 0;
  if (!isv) {
    if (n0 < 768)       { dstqk = q1p; biasp = bq + n0;          ch0 = n0; }
    else if (n0 < 1536) { dstqk = q2p; biasp = bq + n0;          ch0 = n0 - 768; }
    else if (n0 < 2304) { dstqk = k1p; biasp = bk + (n0 - 1536); ch0 = n0 - 1536; }
    else                { dstqk = k2p; biasp = bk + (n0 - 1536); ch0 = n0 - 2304; }
  }
  const float qscl = (n0 < 1536) ? CEXPF : 1.0f;   // fold softmax scale into Q
  const int ch0v = n0 - 3072;

#pragma unroll
  for (int hf = 0; hf < 2; ++hf) {
    __syncthreads();
    if (wn == hf) {
      if (!isv) {
        // tile[m 0..127][col 0..63] (d-major lines), chunk-XOR swizzle by m&3
        float bfv[4];
#pragma unroll
        for (int j = 0; j < 4; ++j) bfv[j] = biasp[hf * 64 + j * 16 + l16];
#pragma unroll
        for (int i = 0; i < 4; ++i)
#pragma unroll
          for (int j = 0; j < 4; ++j) {
            int col = j * 16 + l16;
#pragma unroll
            for (int r = 0; r < 4; ++r) {
              int m = wm * 64 + i * 16 + quad * 4 + r;
              int addr = m * 64 + (col & 15) + ((((col >> 4) ^ (m & 3)) & 3) << 4);
              tile[addr] = f2bu((acc[i][j][r] + bfv[j]) * qscl);
            }
          }
      } else {
        // transposed: tile[d 0..63][s 0..127], chunk-XOR swizzle by d&7
        float bfv[4];
#pragma unroll
        for (int j = 0; j < 4; ++j) bfv[j] = bvp[ch0v + hf * 64 + j * 16 + l16];
#pragma unroll
        for (int i = 0; i < 4; ++i)
#pragma unroll
          for (int j = 0; j < 4; ++j) {
            int d = j * 16 + l16;
#pragma unroll
            for (int r = 0; r < 4; ++r) {
              int m = wm * 64 + i * 16 + quad * 4 + r;   // s within tile
              int addr = d * 128 + (m & 15) + ((((m >> 4) ^ (d & 7)) & 7) << 4);
              tile[addr] = f2bu(acc[i][j][r] + bfv[j]);
            }
          }
      }
    }
    __syncthreads();

    if (!isv) {
      // 128 lines of 128B: line = m (one s, one head); 8 threads x uint4 each
      const int line = t >> 3;
      const int col0 = (t & 7) * 8;
      const int head = (ch0 >> 6) + hf;
#pragma unroll
      for (int p = 0; p < 4; ++p) {
        int m = p * 32 + line;
        int mg = m0 + m;
        if (mg < M_ROWS) {
          int addr = m * 64 + (col0 & 15) + ((((col0 >> 4) ^ (m & 3)) & 3) << 4);
          uint4 v4 = *(const uint4*)(tile + addr);
          int b = mg / 577;
          int s = mg - b * 577;
          *(uint4*)(dstqk + (((size_t)(b * 12 + head) * 577 + s) * 64 + col0)) = v4;
        }
      }
    } else {
      // 64 lines of 256B: line = d; 16 threads x uint4 each (s-contiguous)
      const int line = t >> 4;
      const int col0 = (t & 15) * 8;
      const int hh = (ch0v >> 6) + hf;
#pragma unroll
      for (int p = 0; p < 4; ++p) {
        int d = p * 16 + line;
        int addr = d * 128 + (col0 & 15) + ((((col0 >> 4) ^ (d & 7)) & 7) << 4);
        uint4 v4 = *(const uint4*)(tile + addr);
        int sg0 = m0 + col0;
        int b0 = sg0 / 577, b7 = (sg0 + 7) / 577;
        if (sg0 + 7 < M_ROWS && b0 == b7) {
          *(uint4*)(vtp + (((size_t)(b0 * 12 + hh) * 64 + d) * VT_STRIDE + (sg0 - b0 * 577))) = v4;
        } else {
          const u16* ev = (const u16*)&v4;
          for (int e = 0; e < 8; ++e) {
            int sg = sg0 + e;
            if (sg >= M_ROWS) break;
            int bb = sg / 577;
            vtp[((size_t)(bb * 12 + hh) * 64 + d) * VT_STRIDE + (sg - bb * 577)] = ev[e];
          }
        }
      }
    }
  }
}

// ---------------- flash-style differential attention (no-max softmax) --------
// R8 structure (shared-LDS KV staging, dbuf, source-swizzled) + R12 fusions
// + R13 swapped QK^T (packed b64 P staging, lane-local row-sums).
__global__ __launch_bounds__(256, 4) void attn(
    const u16* __restrict__ q1, const u16* __restrict__ q2,
    const u16* __restrict__ k1, const u16* __restrict__ k2,
    const u16* __restrict__ vt, u16* __restrict__ ctx_t,
    const float* __restrict__ lam_p, float* __restrict__ stats) {
  __shared__ u16 sk1[2][2048];      // [buf][32 kv rows][64], rows 128B, swizzled
  __shared__ u16 sk2[2][2048];
  __shared__ u16 sv[2][2048];       // [buf][64 d rows][32 kv], rows 64B, swizzled
  __shared__ u16 pls[4][2][16 * 40];// per-wave P staging, layout [q][k] pad 40

  const int tid = threadIdx.x;
  const int wave = tid >> 6;
  const int lane = tid & 63;
  const int quad = lane >> 4, l16 = lane & 15;

  // XCD-locality decode: 1920 blocks = 8 xcd * (24 bh * 10 qgroups), bh-major
  const int bid = blockIdx.x;
  const int xcd = bid & 7;
  const int slot = bid >> 3;            // 0..239
  const int bhl = slot / 10;
  const int qgroup = slot - bhl * 10;
  const int bh = xcd * 24 + bhl;
  const int q0 = (qgroup * 4 + wave) * 16;   // may exceed 576 (idle wave)
  const bool active = (q0 < S_LEN);

  const float lam = lam_p[0];
  const size_t qkbase = (size_t)bh * S_LEN * DH;
  const size_t vbase = (size_t)bh * 64 * VT_STRIDE;

  // ---- staging geometry (per thread, constant) ----
  const int krow = tid >> 3;
  const int kelem = ((((tid & 7) << 4) ^ ((krow & 7) << 4)) >> 1); // 0..56
  const u16* k1s = k1 + qkbase + (size_t)krow * 64 + kelem;
  const u16* k2s = k2 + qkbase + (size_t)krow * 64 + kelem;
  const int vrow = tid >> 2;
  const int vel = ((((tid & 3) << 4) ^ ((vrow & 3) << 4)) >> 1);   // 0,8,16,24
  const u16* vs = vt + vbase + (size_t)vrow * VT_STRIDE + vel;
  const int w512 = wave * 512;   // per-wave LDS chunk (1024 B) for staging

  // ---- q fragments (registers, whole kernel) ----
  int qr = q0 + l16; if (qr > 576) qr = 576;   // clamp tail (results discarded)
  bf16x8 q1f[2], q2f[2];
#pragma unroll
  for (int c = 0; c < 2; ++c) {
    q1f[c] = *(const bf16x8*)(q1 + qkbase + (size_t)qr * 64 + c * 32 + quad * 8);
    q2f[c] = *(const bf16x8*)(q2 + qkbase + (size_t)qr * 64 + c * 32 + quad * 8);
  }

  f32x4 zero = {0.f, 0.f, 0.f, 0.f};
  f32x4 O1[4], O2[4];
#pragma unroll
  for (int i = 0; i < 4; ++i) { O1[i] = zero; O2[i] = zero; }
  float l1p = 0.f, l2p = 0.f;   // lane-local partial row-sums (q-row = l16)

  u16* p1w = &pls[wave][0][0];
  u16* p2w = &pls[wave][1][0];

  // read-side swizzle constants
  const int xk = (l16 & 7) << 4;
  const int xv = (l16 & 3) << 4;

  // ---- prologue: stage KV block 0 into buf 0 ----
  gl2lds16(k1s, &sk1[0][0] + w512);
  gl2lds16(k2s, &sk2[0][0] + w512);
  gl2lds16(vs, &sv[0][0] + w512);
  __syncthreads();   // compiler emits vmcnt(0) before s_barrier

  int cur = 0;
  for (int kb = 0; kb < 18; ++kb) {
    // stage next KV block into buf cur^1 (async; drained at the barrier)
    if (kb < 17) {
      gl2lds16(k1s + (kb + 1) * 2048, &sk1[cur ^ 1][0] + w512);
      gl2lds16(k2s + (kb + 1) * 2048, &sk2[cur ^ 1][0] + w512);
      gl2lds16(vs + (kb + 1) * 32, &sv[cur ^ 1][0] + w512);
    } else {
      // final block: all K rows clamp to row 576 (masked in the peel)
      gl2lds16(k1 + qkbase + 576 * 64 + kelem, &sk1[cur ^ 1][0] + w512);
      gl2lds16(k2 + qkbase + 576 * 64 + kelem, &sk2[cur ^ 1][0] + w512);
      gl2lds16(vs + 576, &sv[cur ^ 1][0] + w512);
    }

    if (active) {
      // LDS -> register fragments (swizzled reads)
      const char* bk1 = (const char*)&sk1[cur][0];
      const char* bk2 = (const char*)&sk2[cur][0];
      const char* bv = (const char*)&sv[cur][0];
      bf16x8 k1f[2][2], k2f[2][2], vf[4];
#pragma unroll
      for (int tt = 0; tt < 2; ++tt) {
        int rb = (tt * 16 + l16) * 128;
        k1f[tt][0] = *(const bf16x8*)(bk1 + rb + ((quad * 16) ^ xk));
        k1f[tt][1] = *(const bf16x8*)(bk1 + rb + ((64 + quad * 16) ^ xk));
        k2f[tt][0] = *(const bf16x8*)(bk2 + rb + ((quad * 16) ^ xk));
        k2f[tt][1] = *(const bf16x8*)(bk2 + rb + ((64 + quad * 16) ^ xk));
      }
#pragma unroll
      for (int tt = 0; tt < 4; ++tt)
        vf[tt] = *(const bf16x8*)(bv + (tt * 16 + l16) * 64 + ((quad * 16) ^ xv));

      f32x4 s1[2], s2[2];
      __builtin_amdgcn_s_setprio(1);
#pragma unroll
      for (int tt = 0; tt < 2; ++tt) {
        s1[tt] = __builtin_amdgcn_mfma_f32_16x16x32_bf16(k1f[tt][0], q1f[0], zero, 0, 0, 0);
        s1[tt] = __builtin_amdgcn_mfma_f32_16x16x32_bf16(k1f[tt][1], q1f[1], s1[tt], 0, 0, 0);
        s2[tt] = __builtin_amdgcn_mfma_f32_16x16x32_bf16(k2f[tt][0], q2f[0], zero, 0, 0, 0);
        s2[tt] = __builtin_amdgcn_mfma_f32_16x16x32_bf16(k2f[tt][1], q2f[1], s2[tt], 0, 0, 0);
      }
      __builtin_amdgcn_s_setprio(0);

      // exp + lane-local sums + packed b64 P staging.
      // s[tt][i] = S[k = kv0 + tt*16 + quad*4 + i][q = l16]  (swapped C layout)
#pragma unroll
      for (int tt = 0; tt < 2; ++tt) {
        float pa[4], pb[4];
#pragma unroll
        for (int i = 0; i < 4; ++i) {
          pa[i] = exp2f(s1[tt][i]); l1p += pa[i];
          pb[i] = exp2f(s2[tt][i]); l2p += pb[i];
        }
        // truncating bf16 convert (cheap; ~0.1% bias, well under budget)
        uint2 wa, wb;
        wa.x = (__float_as_uint(pa[1]) & 0xffff0000u) | (__float_as_uint(pa[0]) >> 16);
        wa.y = (__float_as_uint(pa[3]) & 0xffff0000u) | (__float_as_uint(pa[2]) >> 16);
        wb.x = (__float_as_uint(pb[1]) & 0xffff0000u) | (__float_as_uint(pb[0]) >> 16);
        wb.y = (__float_as_uint(pb[3]) & 0xffff0000u) | (__float_as_uint(pb[2]) >> 16);
        *(uint2*)(p1w + l16 * 40 + tt * 16 + quad * 4) = wa;
        *(uint2*)(p2w + l16 * 40 + tt * 16 + quad * 4) = wb;
      }
      bf16x8 p1a = *(const bf16x8*)(p1w + l16 * 40 + quad * 8);
      bf16x8 p2a = *(const bf16x8*)(p2w + l16 * 40 + quad * 8);
      __builtin_amdgcn_s_setprio(1);
#pragma unroll
      for (int tt = 0; tt < 4; ++tt) {
        O1[tt] = __builtin_amdgcn_mfma_f32_16x16x32_bf16(p1a, vf[tt], O1[tt], 0, 0, 0);
        O2[tt] = __builtin_amdgcn_mfma_f32_16x16x32_bf16(p2a, vf[tt], O2[tt], 0, 0, 0);
      }
      __builtin_amdgcn_s_setprio(0);
    }
    __syncthreads();
    cur ^= 1;
  }

  if (active) {
    // ---- peeled final block (kv0 = 576): every staged row holds K[576];
    // only (quad==0, i==0) contributes (k == 576).
    {
      const char* bk1 = (const char*)&sk1[cur][0];
      const char* bk2 = (const char*)&sk2[cur][0];
      const char* bv = (const char*)&sv[cur][0];
      int rb = l16 * 128;
      bf16x8 ka0 = *(const bf16x8*)(bk1 + rb + ((quad * 16) ^ xk));
      bf16x8 ka1 = *(const bf16x8*)(bk1 + rb + ((64 + quad * 16) ^ xk));
      bf16x8 kb0 = *(const bf16x8*)(bk2 + rb + ((quad * 16) ^ xk));
      bf16x8 kb1 = *(const bf16x8*)(bk2 + rb + ((64 + quad * 16) ^ xk));
      f32x4 s1t = __builtin_amdgcn_mfma_f32_16x16x32_bf16(ka0, q1f[0], zero, 0, 0, 0);
      s1t = __builtin_amdgcn_mfma_f32_16x16x32_bf16(ka1, q1f[1], s1t, 0, 0, 0);
      f32x4 s2t = __builtin_amdgcn_mfma_f32_16x16x32_bf16(kb0, q2f[0], zero, 0, 0, 0);
      s2t = __builtin_amdgcn_mfma_f32_16x16x32_bf16(kb1, q2f[1], s2t, 0, 0, 0);
      bf16x8 vf[4];
#pragma unroll
      for (int tt = 0; tt < 4; ++tt)
        vf[tt] = *(const bf16x8*)(bv + (tt * 16 + l16) * 64 + ((quad * 16) ^ xv));
      bool okp = (quad == 0);
      float pa[4], pb[4];
#pragma unroll
      for (int i = 0; i < 4; ++i) {
        pa[i] = (okp && i == 0) ? exp2f(s1t[i]) : 0.f;
        pb[i] = (okp && i == 0) ? exp2f(s2t[i]) : 0.f;
        l1p += pa[i]; l2p += pb[i];
      }
      uint2 wa, wb, wz;
      wa.x = (__float_as_uint(pa[1]) & 0xffff0000u) | (__float_as_uint(pa[0]) >> 16);
      wa.y = (__float_as_uint(pa[3]) & 0xffff0000u) | (__float_as_uint(pa[2]) >> 16);
      wb.x = (__float_as_uint(pb[1]) & 0xffff0000u) | (__float_as_uint(pb[0]) >> 16);
      wb.y = (__float_as_uint(pb[3]) & 0xffff0000u) | (__float_as_uint(pb[2]) >> 16);
      wz.x = 0; wz.y = 0;
      *(uint2*)(p1w + l16 * 40 + quad * 4) = wa;        // k 0..15 region
      *(uint2*)(p1w + l16 * 40 + 16 + quad * 4) = wz;   // k 16..31 region = 0
      *(uint2*)(p2w + l16 * 40 + quad * 4) = wb;
      *(uint2*)(p2w + l16 * 40 + 16 + quad * 4) = wz;
      bf16x8 p1a = *(const bf16x8*)(p1w + l16 * 40 + quad * 8);
      bf16x8 p2a = *(const bf16x8*)(p2w + l16 * 40 + quad * 8);
#pragma unroll
      for (int tt = 0; tt < 4; ++tt) {
        O1[tt] = __builtin_amdgcn_mfma_f32_16x16x32_bf16(p1a, vf[tt], O1[tt], 0, 0, 0);
        O2[tt] = __builtin_amdgcn_mfma_f32_16x16x32_bf16(p2a, vf[tt], O2[tt], 0, 0, 0);
      }
    }

    // full row-sums: combine the 4 quads holding the same q-row (l16)
    l1p += __shfl_xor(l1p, 16); l1p += __shfl_xor(l1p, 32);
    l2p += __shfl_xor(l2p, 16); l2p += __shfl_xor(l2p, 32);
    float inv1 = 1.f / l1p, inv2 = 1.f / l2p;   // valid for q-row = l16
    float a1[4], a2[4];
#pragma unroll
    for (int i = 0; i < 4; ++i) {
      a1[i] = __shfl(inv1, quad * 4 + i);   // lane (quad*4+i) holds q-row quad*4+i
      a2[i] = __shfl(inv2, quad * 4 + i);
    }

    float ssum = 0.f, ssq = 0.f;   // fused GroupNorm partial stats (fp32)
#pragma unroll
    for (int tt = 0; tt < 4; ++tt) {
      size_t cb = ((size_t)bh * 64 + tt * 16 + l16) * S_LEN;
#pragma unroll
      for (int i = 0; i < 4; ++i) {
        int s = q0 + quad * 4 + i;
        if (s < S_LEN) {
          float val = O1[tt][i] * a1[i] - lam * O2[tt][i] * a2[i];
          ctx_t[cb + s] = f2bu(val);
          ssum += val; ssq += val * val;
        }
      }
    }
#pragma unroll
    for (int d = 1; d < 64; d <<= 1) {
      ssum += __shfl_xor(ssum, d);
      ssq += __shfl_xor(ssq, d);
    }
    if (lane == 0) {
      atomicAdd(&stats[bh * 2], ssum);
      atomicAdd(&stats[bh * 2 + 1], ssq);
    }
  }
}

// ---------------- GroupNorm over (b,h): single pass (stats fused in attn) ---
// ctx_t [B,H,64,S] -> context flat [B][D*S] (== reference's reinterpret trick)
__global__ __launch_bounds__(256) void gnorm(
    const u16* __restrict__ ctx_t, u16* __restrict__ context,
    const float* __restrict__ gw, const float* __restrict__ gb,
    const float* __restrict__ stats) {
  const int bh = blockIdx.x;
  const int h = bh % 12;
  const int NEL = 64 * S_LEN;          // 36928
  const int NV = NEL / 8;              // 4616
  const u16* src = ctx_t + (size_t)bh * NEL;
  const float ts = stats[bh * 2];
  const float tq = stats[bh * 2 + 1];
  const float Ninv = 1.0f / (float)NEL;
  const float mu = ts * Ninv;
  const float var = tq * Ninv - mu * mu;
  const float rstd = rsqrtf(var + 1e-5f);
  __shared__ float wv[64], bv2[64];
  if (threadIdx.x < 64) {
    float w = gw[h * 64 + threadIdx.x] * rstd;
    wv[threadIdx.x] = w;
    bv2[threadIdx.x] = gb[h * 64 + threadIdx.x] - mu * w;
  }
  __syncthreads();
  u16* dst = context + (size_t)bh * NEL;   // b*(768*577) + h*(64*577)
  for (int v = threadIdx.x; v < NV; v += 256) {
    uint4 raw = *(const uint4*)(src + v * 8);
    uint32_t w[4] = {raw.x, raw.y, raw.z, raw.w};
    int base = v * 8;
    int d0 = base / 577;
    int r0 = base - d0 * 577;
    u16 o[8];
#pragma unroll
    for (int j = 0; j < 4; ++j) {
#pragma unroll
      for (int e = 0; e < 2; ++e) {
        int ii = j * 2 + e;
        int dd = (r0 + ii >= 577) ? d0 + 1 : d0;
        float f = bu2f((u16)(e == 0 ? (w[j] & 0xffff) : (w[j] >> 16)));
        o[ii] = f2bu(f * wv[dd] + bv2[dd]);
      }
    }
    *(uint4*)(dst + base) = *(const uint4*)o;
  }
}

extern "C" void kernel_launch(void* const* d_in, const int* in_sizes, int n_in,
                              void* d_out, int out_size, void* d_ws, size_t ws_size,
                              hipStream_t stream) {
  const float* x   = (const float*)d_in[0];
  const float* Wq  = (const float*)d_in[1];
  const float* bq  = (const float*)d_in[2];
  const float* Wk  = (const float*)d_in[3];
  const float* bk  = (const float*)d_in[4];
  const float* Wv  = (const float*)d_in[5];
  const float* bv  = (const float*)d_in[6];
  const float* Wo  = (const float*)d_in[7];
  const float* bo  = (const float*)d_in[8];
  const float* lam = (const float*)d_in[9];
  const float* gw  = (const float*)d_in[10];
  const float* gb  = (const float*)d_in[11];
  float* out = (float*)d_out;

  char* p = (char*)d_ws;
  auto alloc = [&](size_t bytes) {
    char* r = p;
    p += (bytes + 255) & ~(size_t)255;
    return r;
  };
  u16* xb     = (u16*)alloc((size_t)M_PAD * 768 * 2);   // also reused as ctxbuf
  u16* wtqkv  = (u16*)alloc((size_t)3840 * 768 * 2);
  u16* wot    = (u16*)alloc((size_t)768 * 768 * 2);
  u16* q1b    = (u16*)alloc((size_t)192 * 577 * 64 * 2);
  u16* q2b    = (u16*)alloc((size_t)192 * 577 * 64 * 2);
  u16* k1b    = (u16*)alloc((size_t)192 * 577 * 64 * 2);
  u16* k2b    = (u16*)alloc((size_t)192 * 577 * 64 * 2);
  u16* vtb    = (u16*)alloc((size_t)192 * 64 * VT_STRIDE * 2);
  u16* ctxt   = (u16*)alloc((size_t)192 * 64 * S_LEN * 2);
  float* stats = (float*)alloc((size_t)192 * 2 * 4);
  u16* ctxbuf = xb;   // alias: xb is dead after the QKV GEMM; keeps ws ~108 MB

  prep_x<<<(M_PAD * 768 / 8 + 255) / 256, 256, 0, stream>>>(x, xb, stats);
  prep_w<<<3456, 256, 0, stream>>>(Wq, Wk, Wv, Wo, wtqkv, wot);

  gemm_bf16<<<dim3(73, 30), 256, 0, stream>>>(xb, wtqkv, 3840, 1,
      nullptr, nullptr, q1b, q2b, k1b, k2b, vtb, bq, bk, bv);

  attn<<<dim3(1920), 256, 0, stream>>>(q1b, q2b, k1b, k2b, vtb, ctxt, lam, stats);

  gnorm<<<192, 256, 0, stream>>>(ctxt, ctxbuf, gw, gb, stats);

  gemm_bf16<<<dim3(73, 6), 256, 0, stream>>>(ctxbuf, wot, 768, 0,
      out, bo, nullptr, nullptr, nullptr, nullptr, nullptr, nullptr, nullptr, nullptr);
}

// Round 12
// 292.818 us; speedup vs baseline: 1.0093x; 1.0093x over previous
//
#include <hip/hip_runtime.h>
#include <hip/hip_bf16.h>
#include <stdint.h>

typedef unsigned short u16;
typedef __attribute__((ext_vector_type(8))) short bf16x8;
typedef __attribute__((ext_vector_type(4))) float f32x4;

#define S_LEN 577
#define DMODEL 768
#define NHEAD 12
#define DH 64
#define BATCH 16
#define M_ROWS (BATCH * S_LEN)   /* 9232 */
#define M_PAD 9344               /* 73 * 128 */
#define VT_STRIDE 640            /* padded S so 16B frag loads stay aligned */
#define CEXPF 0.18033688f        /* 0.125 * log2(e), folded into Q at the GEMM */

__device__ __forceinline__ u16 f2bu(float f) {
  uint32_t u = __float_as_uint(f);
  u += 0x7FFFu + ((u >> 16) & 1u);      // RNE; inputs are finite
  return (u16)(u >> 16);
}
__device__ __forceinline__ float bu2f(u16 b) {
  return __uint_as_float(((uint32_t)b) << 16);
}
// async global->LDS, 16B per lane; LDS dest = wave-uniform base + lane*16
__device__ __forceinline__ void gl2lds16(const u16* g, u16* l) {
  __builtin_amdgcn_global_load_lds(
      (const __attribute__((address_space(1))) unsigned int*)g,
      (__attribute__((address_space(3))) unsigned int*)l, 16, 0, 0);
}

// ---------------- prep: x fp32 -> bf16 [M_PAD,768], pad rows zeroed ----------
// R12: also zeroes the gnorm stats buffer (192*2 floats) before attn runs.
__global__ __launch_bounds__(256) void prep_x(const float* __restrict__ x,
                                              u16* __restrict__ xb,
                                              float* __restrict__ stats) {
  if (blockIdx.x == 0 && threadIdx.x < 384) stats[threadIdx.x] = 0.f;
  int e = (blockIdx.x * 256 + threadIdx.x) * 8;
  u16 o[8];
  if (e < M_ROWS * DMODEL) {
    float4 f0 = *(const float4*)(x + e);
    float4 f1 = *(const float4*)(x + e + 4);
    o[0] = f2bu(f0.x); o[1] = f2bu(f0.y); o[2] = f2bu(f0.z); o[3] = f2bu(f0.w);
    o[4] = f2bu(f1.x); o[5] = f2bu(f1.y); o[6] = f2bu(f1.z); o[7] = f2bu(f1.w);
  } else {
#pragma unroll
    for (int i = 0; i < 8; ++i) o[i] = 0;
  }
  *(uint4*)(xb + e) = *(const uint4*)o;
}

// ------------- prep: weights fp32 [K,N] -> bf16 transposed [N,K], tiled ------
// wtqkv rows: [0,1536)=Wq^T, [1536,3072)=Wk^T, [3072,3840)=Wv^T ; wot = Wo^T
__global__ __launch_bounds__(256) void prep_w(
    const float* __restrict__ Wq, const float* __restrict__ Wk,
    const float* __restrict__ Wv, const float* __restrict__ Wo,
    u16* __restrict__ wtqkv, u16* __restrict__ wot) {
  __shared__ u16 tile[32][33];
  int blk = blockIdx.x;
  const float* W; int N; u16* dst; int rowbase;
  if (blk < 1152)      { W = Wq; N = 1536; dst = wtqkv; rowbase = 0; }
  else if (blk < 2304) { W = Wk; N = 1536; dst = wtqkv; rowbase = 1536; blk -= 1152; }
  else if (blk < 2880) { W = Wv; N = 768;  dst = wtqkv; rowbase = 3072; blk -= 2304; }
  else                 { W = Wo; N = 768;  dst = wot;   rowbase = 0;    blk -= 2880; }
  const int ntiles = N >> 5;
  const int tk = blk / ntiles, tn = blk - tk * ntiles;
  const int c = threadIdx.x & 31, r0 = threadIdx.x >> 5;
#pragma unroll
  for (int i = 0; i < 4; ++i) {
    int r = i * 8 + r0;
    tile[r][c] = f2bu(W[(size_t)(tk * 32 + r) * N + tn * 32 + c]);
  }
  __syncthreads();
#pragma unroll
  for (int i = 0; i < 4; ++i) {
    int r = i * 8 + r0;
    dst[(size_t)(rowbase + tn * 32 + r) * 768 + tk * 32 + c] = tile[c][r];
  }
}

// ---------------- bf16 MFMA GEMM: C[M,N] = A[M,768] * Bt[N,768]^T ------------
// mode 0: out fp32 [M_ROWS,N] + biasO[n]  (output projection)
// mode 1: LDS-staged coalesced scatter (R9) -> q1/q2/k1/k2 + vt.
// R10: bijective XCD/chunk swizzle. R12: q1/q2 pre-scaled by CEXPF.
// R14: T2 XOR-swizzle on staging. R15: T4 counted-vmcnt 3-buffer pipeline.
__global__ __launch_bounds__(256, 2) void gemm_bf16(
    const u16* __restrict__ A, const u16* __restrict__ Bt, int N, int mode,
    float* __restrict__ outF, const float* __restrict__ biasO,
    u16* __restrict__ q1p, u16* __restrict__ q2p,
    u16* __restrict__ k1p, u16* __restrict__ k2p, u16* __restrict__ vtp,
    const float* __restrict__ bq, const float* __restrict__ bk,
    const float* __restrict__ bvp) {
  __shared__ __align__(16) u16 smem[24576];  // 48KB: 3 x (lA 4096 | lB 4096)
  const int t = threadIdx.x;
  const int lane = t & 63, wave = t >> 6;
  const int quad = lane >> 4, l16 = lane & 15;
  const int wm = wave & 1, wn = wave >> 1;

  // ---- XCD-locality swizzle (bijective; perf-only) ----
  const int NTg = gridDim.y;
  const int nwg = 73 * NTg;
  const int lin = blockIdx.y * 73 + blockIdx.x;   // dispatch-linear (x fastest)
  const int xcd8 = lin & 7;
  const int idx8 = lin >> 3;
  const int qq = nwg >> 3, rr = nwg & 7;
  const int slot = (xcd8 < rr) ? xcd8 * (qq + 1) + idx8
                               : rr * (qq + 1) + (xcd8 - rr) * qq + idx8;
  const int C = (NTg >= 10) ? 5 : NTg;   // 30 -> 6 chunks of 5; 6 -> 1 chunk
  const int bpc = 73 * C;
  const int chunk = slot / bpc;
  const int rem = slot - chunk * bpc;
  const int mt = rem / C;
  const int nt = chunk * C + (rem - mt * C);
  const int m0 = mt * 128;
  const int n0 = nt * 128;

  f32x4 zero = {0.f, 0.f, 0.f, 0.f};
  f32x4 acc[4][4];
  for (int i = 0; i < 4; ++i) for (int j = 0; j < 4; ++j) acc[i][j] = zero;

  // staging: wave w owns rows w*32..w*32+31 (2 chunks of 16 rows);
  // lane -> row srow, 16B slot (lane&3) XOR'd with (srow>>1)&3 on the SOURCE
  const int srow = wave * 32 + (lane >> 2);
  const int scol = ((lane & 3) ^ ((srow >> 1) & 3)) * 8;
  const u16* gA = A + (size_t)(m0 + srow) * 768 + scol;
  const u16* gB = Bt + (size_t)(n0 + srow) * 768 + scol;
  const int wofs = wave * 1024;
  // read-side swizzled slot offset (constant per lane)
  const int xs = (quad ^ ((l16 >> 1) & 3)) * 8;

  // ---- prologue: stage K-tiles 0 and 1 into bufs 0,1 (8 loads in flight) ----
  {
    u16* sA0 = smem + wofs;
    u16* sB0 = smem + 4096 + wofs;
    gl2lds16(gA, sA0);
    gl2lds16(gA + 16 * 768, sA0 + 512);
    gl2lds16(gB, sB0);
    gl2lds16(gB + 16 * 768, sB0 + 512);
    u16* sA1 = smem + 8192 + wofs;
    u16* sB1 = smem + 8192 + 4096 + wofs;
    gl2lds16(gA + 32, sA1);
    gl2lds16(gA + 32 + 16 * 768, sA1 + 512);
    gl2lds16(gB + 32, sB1);
    gl2lds16(gB + 32 + 16 * 768, sB1 + 512);
  }
  asm volatile("s_waitcnt vmcnt(4)" ::: "memory");   // tile 0 landed
  __builtin_amdgcn_s_barrier();
  __builtin_amdgcn_sched_barrier(0);

  int cur = 0;
  for (int k0 = 0; k0 < 768; k0 += 32) {
    // stage tile k+2 into buf (cur+2)%3 — stays in flight across the barrier
    if (k0 < 704) {
      int nx2 = cur + 2; if (nx2 >= 3) nx2 -= 3;
      u16* sA = smem + nx2 * 8192 + wofs;
      u16* sB = smem + nx2 * 8192 + 4096 + wofs;
      gl2lds16(gA + k0 + 64, sA);
      gl2lds16(gA + k0 + 64 + 16 * 768, sA + 512);
      gl2lds16(gB + k0 + 64, sB);
      gl2lds16(gB + k0 + 64 + 16 * 768, sB + 512);
    }
    const u16* cA = smem + cur * 8192;
    const u16* cB = smem + cur * 8192 + 4096;
    bf16x8 af[4], bfr[4];
#pragma unroll
    for (int i = 0; i < 4; ++i)
      af[i] = *(const bf16x8*)(cA + (wm * 64 + i * 16 + l16) * 32 + xs);
#pragma unroll
    for (int j = 0; j < 4; ++j)
      bfr[j] = *(const bf16x8*)(cB + (wn * 64 + j * 16 + l16) * 32 + xs);
#pragma unroll
    for (int i = 0; i < 4; ++i)
#pragma unroll
      for (int j = 0; j < 4; ++j)
        acc[i][j] = __builtin_amdgcn_mfma_f32_16x16x32_bf16(af[i], bfr[j], acc[i][j], 0, 0, 0);
    // wait only for tile k+1's loads (oldest 4); k+2's 4 stay in flight
    if (k0 < 704) {
      asm volatile("s_waitcnt vmcnt(4)" ::: "memory");
    } else {
      asm volatile("s_waitcnt vmcnt(0)" ::: "memory");
    }
    __builtin_amdgcn_s_barrier();
    __builtin_amdgcn_sched_barrier(0);
    cur = (cur == 2) ? 0 : cur + 1;
  }

  if (mode == 0) {
#pragma unroll
    for (int i = 0; i < 4; ++i) {
#pragma unroll
      for (int j = 0; j < 4; ++j) {
        int n = n0 + wn * 64 + j * 16 + l16;
#pragma unroll
        for (int r = 0; r < 4; ++r) {
          int m = m0 + wm * 64 + i * 16 + quad * 4 + r;
          if (m >= M_ROWS) continue;
          outF[(size_t)m * N + n] = acc[i][j][r] + biasO[n];
        }
      }
    }
    return;
  }

  // ---------------- mode 1 epilogue: LDS-staged coalesced writes ------------
  u16* tile = smem;   // first 16 KB, staging data is dead now
  const bool isv = (n0 >= 3072);
  u16* dstqk = nullptr; const float* biasp = nullptr; int ch0 = 0;
  if (!isv) {
    if (n0 < 768)       { dstqk = q1p; biasp = bq + n0;          ch0 = n0; }
    else if (n0 < 1536) { dstqk = q2p; biasp = bq + n0;          ch0 = n0 - 768; }
    else if (n0 < 2304) { dstqk = k1p; biasp = bk + (n0 - 1536); ch0 = n0 - 1536; }
    else                { dstqk = k2p; biasp = bk + (n0 - 1536); ch0 = n0 - 2304; }
  }
  const float qscl = (n0 < 1536) ? CEXPF : 1.0f;   // fold softmax scale into Q
  const int ch0v = n0 - 3072;

#pragma unroll
  for (int hf = 0; hf < 2; ++hf) {
    __syncthreads();
    if (wn == hf) {
      if (!isv) {
        // tile[m 0..127][col 0..63] (d-major lines), chunk-XOR swizzle by m&3
        float bfv[4];
#pragma unroll
        for (int j = 0; j < 4; ++j) bfv[j] = biasp[hf * 64 + j * 16 + l16];
#pragma unroll
        for (int i = 0; i < 4; ++i)
#pragma unroll
          for (int j = 0; j < 4; ++j) {
            int col = j * 16 + l16;
#pragma unroll
            for (int r = 0; r < 4; ++r) {
              int m = wm * 64 + i * 16 + quad * 4 + r;
              int addr = m * 64 + (col & 15) + ((((col >> 4) ^ (m & 3)) & 3) << 4);
              tile[addr] = f2bu((acc[i][j][r] + bfv[j]) * qscl);
            }
          }
      } else {
        // transposed: tile[d 0..63][s 0..127], chunk-XOR swizzle by d&7
        float bfv[4];
#pragma unroll
        for (int j = 0; j < 4; ++j) bfv[j] = bvp[ch0v + hf * 64 + j * 16 + l16];
#pragma unroll
        for (int i = 0; i < 4; ++i)
#pragma unroll
          for (int j = 0; j < 4; ++j) {
            int d = j * 16 + l16;
#pragma unroll
            for (int r = 0; r < 4; ++r) {
              int m = wm * 64 + i * 16 + quad * 4 + r;   // s within tile
              int addr = d * 128 + (m & 15) + ((((m >> 4) ^ (d & 7)) & 7) << 4);
              tile[addr] = f2bu(acc[i][j][r] + bfv[j]);
            }
          }
      }
    }
    __syncthreads();

    if (!isv) {
      // 128 lines of 128B: line = m (one s, one head); 8 threads x uint4 each
      const int line = t >> 3;
      const int col0 = (t & 7) * 8;
      const int head = (ch0 >> 6) + hf;
#pragma unroll
      for (int p = 0; p < 4; ++p) {
        int m = p * 32 + line;
        int mg = m0 + m;
        if (mg < M_ROWS) {
          int addr = m * 64 + (col0 & 15) + ((((col0 >> 4) ^ (m & 3)) & 3) << 4);
          uint4 v4 = *(const uint4*)(tile + addr);
          int b = mg / 577;
          int s = mg - b * 577;
          *(uint4*)(dstqk + (((size_t)(b * 12 + head) * 577 + s) * 64 + col0)) = v4;
        }
      }
    } else {
      // 64 lines of 256B: line = d; 16 threads x uint4 each (s-contiguous)
      const int line = t >> 4;
      const int col0 = (t & 15) * 8;
      const int hh = (ch0v >> 6) + hf;
#pragma unroll
      for (int p = 0; p < 4; ++p) {
        int d = p * 16 + line;
        int addr = d * 128 + (col0 & 15) + ((((col0 >> 4) ^ (d & 7)) & 7) << 4);
        uint4 v4 = *(const uint4*)(tile + addr);
        int sg0 = m0 + col0;
        int b0 = sg0 / 577, b7 = (sg0 + 7) / 577;
        if (sg0 + 7 < M_ROWS && b0 == b7) {
          *(uint4*)(vtp + (((size_t)(b0 * 12 + hh) * 64 + d) * VT_STRIDE + (sg0 - b0 * 577))) = v4;
        } else {
          const u16* ev = (const u16*)&v4;
          for (int e = 0; e < 8; ++e) {
            int sg = sg0 + e;
            if (sg >= M_ROWS) break;
            int bb = sg / 577;
            vtp[((size_t)(bb * 12 + hh) * 64 + d) * VT_STRIDE + (sg - bb * 577)] = ev[e];
          }
        }
      }
    }
  }
}

// ---------------- flash-style differential attention (no-max softmax) --------
// R8 structure + R12 fusions + R13 swapped QK^T.
// R16: 8-WAVE (512-thread) BLOCKS. Each block covers 128 q-rows of one bh
// (grid 1920 -> 960): K/V staged once per 128 q-rows (FETCH halves) and
// 3 blocks/CU x 8 waves = 24 waves/CU potential (was 10 at 32% occ) for
// latency hiding. Per-wave compute pipeline byte-identical; staging stays
// with waves 0-3 (tid<256, geometry unchanged); waves 4-7 only consume.
__global__ __launch_bounds__(512, 4) void attn(
    const u16* __restrict__ q1, const u16* __restrict__ q2,
    const u16* __restrict__ k1, const u16* __restrict__ k2,
    const u16* __restrict__ vt, u16* __restrict__ ctx_t,
    const float* __restrict__ lam_p, float* __restrict__ stats) {
  __shared__ u16 sk1[2][2048];      // [buf][32 kv rows][64], rows 128B, swizzled
  __shared__ u16 sk2[2][2048];
  __shared__ u16 sv[2][2048];       // [buf][64 d rows][32 kv], rows 64B, swizzled
  __shared__ u16 pls[8][2][16 * 40];// per-wave P staging, layout [q][k] pad 40

  const int tid = threadIdx.x;
  const int wave = tid >> 6;
  const int lane = tid & 63;
  const int quad = lane >> 4, l16 = lane & 15;

  // XCD-locality decode: 960 blocks = 8 xcd * (24 bh * 5 qgroups), bh-major
  const int bid = blockIdx.x;
  const int xcd = bid & 7;
  const int slot = bid >> 3;            // 0..119
  const int bhl = slot / 5;
  const int qgroup = slot - bhl * 5;
  const int bh = xcd * 24 + bhl;
  const int q0 = (qgroup * 8 + wave) * 16;   // may exceed 576 (idle wave)
  const bool active = (q0 < S_LEN);

  const float lam = lam_p[0];
  const size_t qkbase = (size_t)bh * S_LEN * DH;
  const size_t vbase = (size_t)bh * 64 * VT_STRIDE;

  // ---- staging geometry (waves 0-3 only; tid < 256 there) ----
  const int krow = (tid & 255) >> 3;
  const int kelem = ((((tid & 7) << 4) ^ ((krow & 7) << 4)) >> 1); // 0..56
  const u16* k1s = k1 + qkbase + (size_t)krow * 64 + kelem;
  const u16* k2s = k2 + qkbase + (size_t)krow * 64 + kelem;
  const int vrow = (tid & 255) >> 2;
  const int vel = ((((tid & 3) << 4) ^ ((vrow & 3) << 4)) >> 1);   // 0,8,16,24
  const u16* vs = vt + vbase + (size_t)vrow * VT_STRIDE + vel;
  const int w512 = (wave & 3) * 512;   // staging wave's LDS chunk (1024 B)
  const bool stg = (wave < 4);

  // ---- q fragments (registers, whole kernel) ----
  int qr = q0 + l16; if (qr > 576) qr = 576;   // clamp tail (results discarded)
  bf16x8 q1f[2], q2f[2];
#pragma unroll
  for (int c = 0; c < 2; ++c) {
    q1f[c] = *(const bf16x8*)(q1 + qkbase + (size_t)qr * 64 + c * 32 + quad * 8);
    q2f[c] = *(const bf16x8*)(q2 + qkbase + (size_t)qr * 64 + c * 32 + quad * 8);
  }

  f32x4 zero = {0.f, 0.f, 0.f, 0.f};
  f32x4 O1[4], O2[4];
#pragma unroll
  for (int i = 0; i < 4; ++i) { O1[i] = zero; O2[i] = zero; }
  float l1p = 0.f, l2p = 0.f;   // lane-local partial row-sums (q-row = l16)

  u16* p1w = &pls[wave][0][0];
  u16* p2w = &pls[wave][1][0];

  // read-side swizzle constants
  const int xk = (l16 & 7) << 4;
  const int xv = (l16 & 3) << 4;

  // ---- prologue: stage KV block 0 into buf 0 ----
  if (stg) {
    gl2lds16(k1s, &sk1[0][0] + w512);
    gl2lds16(k2s, &sk2[0][0] + w512);
    gl2lds16(vs, &sv[0][0] + w512);
  }
  __syncthreads();   // compiler emits vmcnt(0) before s_barrier

  int cur = 0;
  for (int kb = 0; kb < 18; ++kb) {
    // stage next KV block into buf cur^1 (async; drained at the barrier)
    if (stg) {
      if (kb < 17) {
        gl2lds16(k1s + (kb + 1) * 2048, &sk1[cur ^ 1][0] + w512);
        gl2lds16(k2s + (kb + 1) * 2048, &sk2[cur ^ 1][0] + w512);
        gl2lds16(vs + (kb + 1) * 32, &sv[cur ^ 1][0] + w512);
      } else {
        // final block: all K rows clamp to row 576 (masked in the peel)
        gl2lds16(k1 + qkbase + 576 * 64 + kelem, &sk1[cur ^ 1][0] + w512);
        gl2lds16(k2 + qkbase + 576 * 64 + kelem, &sk2[cur ^ 1][0] + w512);
        gl2lds16(vs + 576, &sv[cur ^ 1][0] + w512);
      }
    }

    if (active) {
      // LDS -> register fragments (swizzled reads)
      const char* bk1 = (const char*)&sk1[cur][0];
      const char* bk2 = (const char*)&sk2[cur][0];
      const char* bv = (const char*)&sv[cur][0];
      bf16x8 k1f[2][2], k2f[2][2], vf[4];
#pragma unroll
      for (int tt = 0; tt < 2; ++tt) {
        int rb = (tt * 16 + l16) * 128;
        k1f[tt][0] = *(const bf16x8*)(bk1 + rb + ((quad * 16) ^ xk));
        k1f[tt][1] = *(const bf16x8*)(bk1 + rb + ((64 + quad * 16) ^ xk));
        k2f[tt][0] = *(const bf16x8*)(bk2 + rb + ((quad * 16) ^ xk));
        k2f[tt][1] = *(const bf16x8*)(bk2 + rb + ((64 + quad * 16) ^ xk));
      }
#pragma unroll
      for (int tt = 0; tt < 4; ++tt)
        vf[tt] = *(const bf16x8*)(bv + (tt * 16 + l16) * 64 + ((quad * 16) ^ xv));

      f32x4 s1[2], s2[2];
      __builtin_amdgcn_s_setprio(1);
#pragma unroll
      for (int tt = 0; tt < 2; ++tt) {
        s1[tt] = __builtin_amdgcn_mfma_f32_16x16x32_bf16(k1f[tt][0], q1f[0], zero, 0, 0, 0);
        s1[tt] = __builtin_amdgcn_mfma_f32_16x16x32_bf16(k1f[tt][1], q1f[1], s1[tt], 0, 0, 0);
        s2[tt] = __builtin_amdgcn_mfma_f32_16x16x32_bf16(k2f[tt][0], q2f[0], zero, 0, 0, 0);
        s2[tt] = __builtin_amdgcn_mfma_f32_16x16x32_bf16(k2f[tt][1], q2f[1], s2[tt], 0, 0, 0);
      }
      __builtin_amdgcn_s_setprio(0);

      // exp + lane-local sums + packed b64 P staging.
      // s[tt][i] = S[k = kv0 + tt*16 + quad*4 + i][q = l16]  (swapped C layout)
#pragma unroll
      for (int tt = 0; tt < 2; ++tt) {
        float pa[4], pb[4];
#pragma unroll
        for (int i = 0; i < 4; ++i) {
          pa[i] = exp2f(s1[tt][i]); l1p += pa[i];
          pb[i] = exp2f(s2[tt][i]); l2p += pb[i];
        }
        // truncating bf16 convert (cheap; ~0.1% bias, well under budget)
        uint2 wa, wb;
        wa.x = (__float_as_uint(pa[1]) & 0xffff0000u) | (__float_as_uint(pa[0]) >> 16);
        wa.y = (__float_as_uint(pa[3]) & 0xffff0000u) | (__float_as_uint(pa[2]) >> 16);
        wb.x = (__float_as_uint(pb[1]) & 0xffff0000u) | (__float_as_uint(pb[0]) >> 16);
        wb.y = (__float_as_uint(pb[3]) & 0xffff0000u) | (__float_as_uint(pb[2]) >> 16);
        *(uint2*)(p1w + l16 * 40 + tt * 16 + quad * 4) = wa;
        *(uint2*)(p2w + l16 * 40 + tt * 16 + quad * 4) = wb;
      }
      bf16x8 p1a = *(const bf16x8*)(p1w + l16 * 40 + quad * 8);
      bf16x8 p2a = *(const bf16x8*)(p2w + l16 * 40 + quad * 8);
      __builtin_amdgcn_s_setprio(1);
#pragma unroll
      for (int tt = 0; tt < 4; ++tt) {
        O1[tt] = __builtin_amdgcn_mfma_f32_16x16x32_bf16(p1a, vf[tt], O1[tt], 0, 0, 0);
        O2[tt] = __builtin_amdgcn_mfma_f32_16x16x32_bf16(p2a, vf[tt], O2[tt], 0, 0, 0);
      }
      __builtin_amdgcn_s_setprio(0);
    }
    __syncthreads();
    cur ^= 1;
  }

  if (active) {
    // ---- peeled final block (kv0 = 576): every staged row holds K[576];
    // only (quad==0, i==0) contributes (k == 576).
    {
      const char* bk1 = (const char*)&sk1[cur][0];
      const char* bk2 = (const char*)&sk2[cur][0];
      const char* bv = (const char*)&sv[cur][0];
      int rb = l16 * 128;
      bf16x8 ka0 = *(const bf16x8*)(bk1 + rb + ((quad * 16) ^ xk));
      bf16x8 ka1 = *(const bf16x8*)(bk1 + rb + ((64 + quad * 16) ^ xk));
      bf16x8 kb0 = *(const bf16x8*)(bk2 + rb + ((quad * 16) ^ xk));
      bf16x8 kb1 = *(const bf16x8*)(bk2 + rb + ((64 + quad * 16) ^ xk));
      f32x4 s1t = __builtin_amdgcn_mfma_f32_16x16x32_bf16(ka0, q1f[0], zero, 0, 0, 0);
      s1t = __builtin_amdgcn_mfma_f32_16x16x32_bf16(ka1, q1f[1], s1t, 0, 0, 0);
      f32x4 s2t = __builtin_amdgcn_mfma_f32_16x16x32_bf16(kb0, q2f[0], zero, 0, 0, 0);
      s2t = __builtin_amdgcn_mfma_f32_16x16x32_bf16(kb1, q2f[1], s2t, 0, 0, 0);
      bf16x8 vf[4];
#pragma unroll
      for (int tt = 0; tt < 4; ++tt)
        vf[tt] = *(const bf16x8*)(bv + (tt * 16 + l16) * 64 + ((quad * 16) ^ xv));
      bool okp = (quad == 0);
      float pa[4], pb[4];
#pragma unroll
      for (int i = 0; i < 4; ++i) {
        pa[i] = (okp && i == 0) ? exp2f(s1t[i]) : 0.f;
        pb[i] = (okp && i == 0) ? exp2f(s2t[i]) : 0.f;
        l1p += pa[i]; l2p += pb[i];
      }
      uint2 wa, wb, wz;
      wa.x = (__float_as_uint(pa[1]) & 0xffff0000u) | (__float_as_uint(pa[0]) >> 16);
      wa.y = (__float_as_uint(pa[3]) & 0xffff0000u) | (__float_as_uint(pa[2]) >> 16);
      wb.x = (__float_as_uint(pb[1]) & 0xffff0000u) | (__float_as_uint(pb[0]) >> 16);
      wb.y = (__float_as_uint(pb[3]) & 0xffff0000u) | (__float_as_uint(pb[2]) >> 16);
      wz.x = 0; wz.y = 0;
      *(uint2*)(p1w + l16 * 40 + quad * 4) = wa;        // k 0..15 region
      *(uint2*)(p1w + l16 * 40 + 16 + quad * 4) = wz;   // k 16..31 region = 0
      *(uint2*)(p2w + l16 * 40 + quad * 4) = wb;
      *(uint2*)(p2w + l16 * 40 + 16 + quad * 4) = wz;
      bf16x8 p1a = *(const bf16x8*)(p1w + l16 * 40 + quad * 8);
      bf16x8 p2a = *(const bf16x8*)(p2w + l16 * 40 + quad * 8);
#pragma unroll
      for (int tt = 0; tt < 4; ++tt) {
        O1[tt] = __builtin_amdgcn_mfma_f32_16x16x32_bf16(p1a, vf[tt], O1[tt], 0, 0, 0);
        O2[tt] = __builtin_amdgcn_mfma_f32_16x16x32_bf16(p2a, vf[tt], O2[tt], 0, 0, 0);
      }
    }

    // full row-sums: combine the 4 quads holding the same q-row (l16)
    l1p += __shfl_xor(l1p, 16); l1p += __shfl_xor(l1p, 32);
    l2p += __shfl_xor(l2p, 16); l2p += __shfl_xor(l2p, 32);
    float inv1 = 1.f / l1p, inv2 = 1.f / l2p;   // valid for q-row = l16
    float a1[4], a2[4];
#pragma unroll
    for (int i = 0; i < 4; ++i) {
      a1[i] = __shfl(inv1, quad * 4 + i);   // lane (quad*4+i) holds q-row quad*4+i
      a2[i] = __shfl(inv2, quad * 4 + i);
    }

    float ssum = 0.f, ssq = 0.f;   // fused GroupNorm partial stats (fp32)
#pragma unroll
    for (int tt = 0; tt < 4; ++tt) {
      size_t cb = ((size_t)bh * 64 + tt * 16 + l16) * S_LEN;
#pragma unroll
      for (int i = 0; i < 4; ++i) {
        int s = q0 + quad * 4 + i;
        if (s < S_LEN) {
          float val = O1[tt][i] * a1[i] - lam * O2[tt][i] * a2[i];
          ctx_t[cb + s] = f2bu(val);
          ssum += val; ssq += val * val;
        }
      }
    }
#pragma unroll
    for (int d = 1; d < 64; d <<= 1) {
      ssum += __shfl_xor(ssum, d);
      ssq += __shfl_xor(ssq, d);
    }
    if (lane == 0) {
      atomicAdd(&stats[bh * 2], ssum);
      atomicAdd(&stats[bh * 2 + 1], ssq);
    }
  }
}

// ---------------- GroupNorm over (b,h): single pass (stats fused in attn) ---
// ctx_t [B,H,64,S] -> context flat [B][D*S] (== reference's reinterpret trick)
__global__ __launch_bounds__(256) void gnorm(
    const u16* __restrict__ ctx_t, u16* __restrict__ context,
    const float* __restrict__ gw, const float* __restrict__ gb,
    const float* __restrict__ stats) {
  const int bh = blockIdx.x;
  const int h = bh % 12;
  const int NEL = 64 * S_LEN;          // 36928
  const int NV = NEL / 8;              // 4616
  const u16* src = ctx_t + (size_t)bh * NEL;
  const float ts = stats[bh * 2];
  const float tq = stats[bh * 2 + 1];
  const float Ninv = 1.0f / (float)NEL;
  const float mu = ts * Ninv;
  const float var = tq * Ninv - mu * mu;
  const float rstd = rsqrtf(var + 1e-5f);
  __shared__ float wv[64], bv2[64];
  if (threadIdx.x < 64) {
    float w = gw[h * 64 + threadIdx.x] * rstd;
    wv[threadIdx.x] = w;
    bv2[threadIdx.x] = gb[h * 64 + threadIdx.x] - mu * w;
  }
  __syncthreads();
  u16* dst = context + (size_t)bh * NEL;   // b*(768*577) + h*(64*577)
  for (int v = threadIdx.x; v < NV; v += 256) {
    uint4 raw = *(const uint4*)(src + v * 8);
    uint32_t w[4] = {raw.x, raw.y, raw.z, raw.w};
    int base = v * 8;
    int d0 = base / 577;
    int r0 = base - d0 * 577;
    u16 o[8];
#pragma unroll
    for (int j = 0; j < 4; ++j) {
#pragma unroll
      for (int e = 0; e < 2; ++e) {
        int ii = j * 2 + e;
        int dd = (r0 + ii >= 577) ? d0 + 1 : d0;
        float f = bu2f((u16)(e == 0 ? (w[j] & 0xffff) : (w[j] >> 16)));
        o[ii] = f2bu(f * wv[dd] + bv2[dd]);
      }
    }
    *(uint4*)(dst + base) = *(const uint4*)o;
  }
}

extern "C" void kernel_launch(void* const* d_in, const int* in_sizes, int n_in,
                              void* d_out, int out_size, void* d_ws, size_t ws_size,
                              hipStream_t stream) {
  const float* x   = (const float*)d_in[0];
  const float* Wq  = (const float*)d_in[1];
  const float* bq  = (const float*)d_in[2];
  const float* Wk  = (const float*)d_in[3];
  const float* bk  = (const float*)d_in[4];
  const float* Wv  = (const float*)d_in[5];
  const float* bv  = (const float*)d_in[6];
  const float* Wo  = (const float*)d_in[7];
  const float* bo  = (const float*)d_in[8];
  const float* lam = (const float*)d_in[9];
  const float* gw  = (const float*)d_in[10];
  const float* gb  = (const float*)d_in[11];
  float* out = (float*)d_out;

  char* p = (char*)d_ws;
  auto alloc = [&](size_t bytes) {
    char* r = p;
    p += (bytes + 255) & ~(size_t)255;
    return r;
  };
  u16* xb     = (u16*)alloc((size_t)M_PAD * 768 * 2);   // also reused as ctxbuf
  u16* wtqkv  = (u16*)alloc((size_t)3840 * 768 * 2);
  u16* wot    = (u16*)alloc((size_t)768 * 768 * 2);
  u16* q1b    = (u16*)alloc((size_t)192 * 577 * 64 * 2);
  u16* q2b    = (u16*)alloc((size_t)192 * 577 * 64 * 2);
  u16* k1b    = (u16*)alloc((size_t)192 * 577 * 64 * 2);
  u16* k2b    = (u16*)alloc((size_t)192 * 577 * 64 * 2);
  u16* vtb    = (u16*)alloc((size_t)192 * 64 * VT_STRIDE * 2);
  u16* ctxt   = (u16*)alloc((size_t)192 * 64 * S_LEN * 2);
  float* stats = (float*)alloc((size_t)192 * 2 * 4);
  u16* ctxbuf = xb;   // alias: xb is dead after the QKV GEMM; keeps ws ~108 MB

  prep_x<<<(M_PAD * 768 / 8 + 255) / 256, 256, 0, stream>>>(x, xb, stats);
  prep_w<<<3456, 256, 0, stream>>>(Wq, Wk, Wv, Wo, wtqkv, wot);

  gemm_bf16<<<dim3(73, 30), 256, 0, stream>>>(xb, wtqkv, 3840, 1,
      nullptr, nullptr, q1b, q2b, k1b, k2b, vtb, bq, bk, bv);

  attn<<<dim3(960), 512, 0, stream>>>(q1b, q2b, k1b, k2b, vtb, ctxt, lam, stats);

  gnorm<<<192, 256, 0, stream>>>(ctxt, ctxbuf, gw, gb, stats);

  gemm_bf16<<<dim3(73, 6), 256, 0, stream>>>(ctxbuf, wot, 768, 0,
      out, bo, nullptr, nullptr, nullptr, nullptr, nullptr, nullptr, nullptr, nullptr);
}